// Round 10
// baseline (778.386 us; speedup 1.0000x reference)
//
#include <hip/hip_runtime.h>

#define BN 1000000
#define KN 16384
#define TPB1 512
#define NW1 8
#define CHROWS 256                         // rows per block-chunk in phase1 (8 waves x 32)
#define NB1 512                            // phase1 persistent grid
#define NBC 512                            // sortchain grid (2 blocks/CU co-resident)
#define NBP 512                            // phase23 grid
#define NCHUNK ((BN + CHROWS - 1) / CHROWS)

typedef __bf16 bf16x8 __attribute__((ext_vector_type(8)));
typedef float  f32x4  __attribute__((ext_vector_type(4)));
typedef unsigned short u16x8 __attribute__((ext_vector_type(8)));

__device__ __forceinline__ unsigned short f2bf(float f) {
    return __builtin_bit_cast(unsigned short, (__bf16)f);   // HW v_cvt (RTNE)
}
__device__ __forceinline__ float bf2f(unsigned short b) {
    return (float)__builtin_bit_cast(__bf16, b);
}
__device__ __forceinline__ float silu_f(float v) {
    return v * __builtin_amdgcn_rcpf(1.0f + __expf(-v));
}
__device__ __forceinline__ f32x4 mfma16(bf16x8 a, bf16x8 b, f32x4 c) {
    return __builtin_amdgcn_mfma_f32_16x16x32_bf16(a, b, c, 0, 0, 0);
}

// ---- XLA ErfInv32 polynomial ----
__device__ __forceinline__ float erfinv_xla(float x) {
    float w = -log1pf(-x * x);
    float p;
    if (w < 5.0f) {
        w -= 2.5f;
        p = 2.81022636e-08f;
        p = fmaf(p, w, 3.43273939e-07f);
        p = fmaf(p, w, -3.5233877e-06f);
        p = fmaf(p, w, -4.39150654e-06f);
        p = fmaf(p, w, 0.00021858087f);
        p = fmaf(p, w, -0.00125372503f);
        p = fmaf(p, w, -0.00417768164f);
        p = fmaf(p, w, 0.246640727f);
        p = fmaf(p, w, 1.50140941f);
    } else {
        w = sqrtf(w) - 3.0f;
        p = -0.000200214257f;
        p = fmaf(p, w, 0.000100950558f);
        p = fmaf(p, w, 0.00134934322f);
        p = fmaf(p, w, -0.00367342844f);
        p = fmaf(p, w, 0.00573950773f);
        p = fmaf(p, w, -0.0076224613f);
        p = fmaf(p, w, 0.00943887047f);
        p = fmaf(p, w, 1.00167406f);
        p = fmaf(p, w, 2.83297682f);
    }
    return p * x;
}

// ---- jax.random.normal(key(42), (16384,)), threefry_partitionable: bits = out0^out1 ----
__device__ __forceinline__ float jax_eps16384(int gid) {
    const unsigned k0 = 0u, k1 = 42u, k2 = 0x1BD11BDAu ^ 0u ^ 42u;
    unsigned x0 = 0u + k0;
    unsigned x1 = (unsigned)gid + k1;
#define TF_RND(r) { x0 += x1; x1 = (x1 << (r)) | (x1 >> (32 - (r))); x1 ^= x0; }
    TF_RND(13) TF_RND(15) TF_RND(26) TF_RND(6)  x0 += k1; x1 += k2 + 1u;
    TF_RND(17) TF_RND(29) TF_RND(16) TF_RND(24) x0 += k2; x1 += k0 + 2u;
    TF_RND(13) TF_RND(15) TF_RND(26) TF_RND(6)  x0 += k0; x1 += k1 + 3u;
    TF_RND(17) TF_RND(29) TF_RND(16) TF_RND(24) x0 += k1; x1 += k2 + 4u;
    TF_RND(13) TF_RND(15) TF_RND(26) TF_RND(6)  x0 += k2; x1 += k0 + 5u;
#undef TF_RND
    unsigned bits = x0 ^ x1;
    float f = __uint_as_float((bits >> 9) | 0x3f800000u) - 1.0f;
    const float mn = -0.99999994f;
    float u = fmaxf(f * 2.0f + mn, mn);
    return 1.41421354f * erfinv_xla(u);
}

// ---- grid barrier (generation counter), agent-scope fenced — round-8-proven ----
__device__ __forceinline__ void gridbar(int* cnt, int* gen, int nblk) {
    __syncthreads();
    if (threadIdx.x == 0) {
        __threadfence();   // release: drain + L2 writeback (agent scope)
        int g = __hip_atomic_load(gen, __ATOMIC_ACQUIRE, __HIP_MEMORY_SCOPE_AGENT);
        int a = __hip_atomic_fetch_add(cnt, 1, __ATOMIC_ACQ_REL, __HIP_MEMORY_SCOPE_AGENT);
        if (a == nblk - 1) {
            __hip_atomic_store(cnt, 0, __ATOMIC_RELAXED, __HIP_MEMORY_SCOPE_AGENT);
            __hip_atomic_fetch_add(gen, 1, __ATOMIC_RELEASE, __HIP_MEMORY_SCOPE_AGENT);
        } else {
            while (__hip_atomic_load(gen, __ATOMIC_ACQUIRE, __HIP_MEMORY_SCOPE_AGENT) == g)
                __builtin_amdgcn_s_sleep(1);
        }
        __threadfence();   // acquire side
    }
    __syncthreads();
}

// ============ fused sort chain: zero+histogram | scan | convert+scatter-write ============
__global__ __launch_bounds__(256) void k_sortchain(
    const int* __restrict__ gl, const float* __restrict__ x,
    int* __restrict__ counts, int* __restrict__ cursor,
    int* __restrict__ sgr, unsigned short* __restrict__ xb,
    float4* __restrict__ gsumz, int* __restrict__ bar)
{
    const int t = threadIdx.x;
    const int gtid = blockIdx.x * 256 + t;
    const int NT = NBC * 256;

    // ---- phase B: zero gsum (ordering to phase1 via kernel boundary) + histogram ----
    {
        const float4 z4 = make_float4(0.f, 0.f, 0.f, 0.f);
        for (int i = gtid; i < KN * 64 / 4; i += NT) gsumz[i] = z4;
        for (int i = gtid; i < BN / 4; i += NT) {
            int4 g = ((const int4*)gl)[i];
            atomicAdd(&counts[g.x], 1); atomicAdd(&counts[g.y], 1);
            atomicAdd(&counts[g.z], 1); atomicAdd(&counts[g.w], 1);
        }
    }
    gridbar(bar, bar + 1, NBC);

    // ---- phase C: exclusive scan (block 0; 256 threads x 64 counts, two-pass) ----
    if (blockIdx.x == 0) {
        __shared__ int wt[4];
        const int lane = t & 63, wv = t >> 6;
        const int4* c4 = (const int4*)counts;
        int sum = 0;
        #pragma unroll
        for (int i = 0; i < 16; ++i) {
            int4 q = c4[t * 16 + i];
            sum += q.x + q.y + q.z + q.w;
        }
        int inc = sum;
        #pragma unroll
        for (int off = 1; off < 64; off <<= 1) {
            int v = __shfl_up(inc, off);
            if (lane >= off) inc += v;
        }
        if (lane == 63) wt[wv] = inc;
        __syncthreads();
        int wb = 0;
        #pragma unroll
        for (int w = 0; w < 4; ++w) wb += (w < wv) ? wt[w] : 0;
        int run = wb + inc - sum;
        int4* cu4 = (int4*)cursor;
        #pragma unroll
        for (int i = 0; i < 16; ++i) {
            int4 q = c4[t * 16 + i];
            int4 o;
            o.x = run; o.y = run + q.x; o.z = o.y + q.y; o.w = o.z + q.z;
            run = o.w + q.w;
            cu4[t * 16 + i] = o;
        }
    }
    gridbar(bar, bar + 1, NBC);

    // ---- phase D: stream x, convert bf16, scatter-write full rows to sorted slots ----
    {
        const int lane = t & 63;
        const int wgid = gtid >> 6;          // 0..2047
        const int sub  = lane >> 4;          // row-in-4
        const int q16  = lane & 15;          // 16B slot in row
        const int WSTRIDE = (NBC * 256 / 64) * 4;   // 8192 rows per sweep
        for (int base = wgid * 4; base < BN; base += WSTRIDE) {
            int row = base + sub;            // BN % 4 == 0 -> always < BN
            float4 v = *(const float4*)(x + (size_t)row * 64 + q16 * 4);
            int g = gl[row];
            int p = 0;
            if (q16 == 0) p = atomicAdd(&cursor[g], 1);
            p = __shfl(p, sub * 16);
            if (q16 == 0) sgr[p] = g;
            ushort4 pk;
            pk.x = f2bf(v.x); pk.y = f2bf(v.y); pk.z = f2bf(v.z); pk.w = f2bf(v.w);
            *(ushort4*)((char*)xb + (size_t)p * 128 + q16 * 8) = pk;   // 2 full lines/row
        }
    }
}

// ============ phase 1: STREAMING MLP over sorted bf16 rows + segmented reduce ============
__global__ __launch_bounds__(TPB1, 4) void k_phase1(
    const unsigned short* __restrict__ xb, const int* __restrict__ sgr,
    const float* __restrict__ W1, const float* __restrict__ b1,
    const float* __restrict__ W2, const float* __restrict__ b2,
    float* __restrict__ gsum)
{
    __shared__ __align__(16) unsigned short w1t[64 * 64];    // [j][k] bf16, swizzled
    __shared__ __align__(16) unsigned short w2t[64 * 64];
    __shared__ __align__(16) unsigned short xh[NW1][32 * 64]; // per-wave: h1 then zT
    __shared__ float b1s[64], b2s[64];
    __shared__ int sg_s[NW1][32];

    const int t = threadIdx.x;
    const int wv = t >> 6, lane = t & 63;
    const int lj = lane & 15, lg = lane >> 4;

    // ---- stage W1^T, W2^T (bf16, swizzled) — once per block ----
    {
        const float4* W1v = (const float4*)W1;
        const float4* W2v = (const float4*)W2;
        #pragma unroll
        for (int i = 0; i < 2; ++i) {
            int e4 = i * TPB1 + t;
            int k  = e4 >> 4;
            int j0 = (e4 & 15) * 4;
            float4 a = W1v[e4];
            float4 b = W2v[e4];
            float av[4] = {a.x, a.y, a.z, a.w};
            float bv[4] = {b.x, b.y, b.z, b.w};
            #pragma unroll
            for (int c = 0; c < 4; ++c) {
                int j = j0 + c;
                int off = j * 128 + ((2 * k) ^ ((j & 7) << 4));
                *(unsigned short*)((char*)w1t + off) = f2bf(av[c]);
                *(unsigned short*)((char*)w2t + off) = f2bf(bv[c]);
            }
        }
        if (t < 64) { b1s[t] = b1[t]; b2s[t] = b2[t]; }
    }
    __syncthreads();   // the ONLY block barrier (startup)

    float bc1[4], bc2[4];
    #pragma unroll
    for (int ct = 0; ct < 4; ++ct) { bc1[ct] = b1s[ct * 16 + lj]; bc2[ct] = b2s[ct * 16 + lj]; }

    unsigned short* myx = &xh[wv][0];

    for (int c = blockIdx.x; c < NCHUNK; c += NB1) {
        const int r0 = c * CHROWS + wv * 32;
        // groups for this wave's 32 rows
        if (lg == 0) {
            #pragma unroll
            for (int rt = 0; rt < 2; ++rt) {
                int r = r0 + rt * 16 + lj;
                sg_s[wv][rt * 16 + lj] = (r < BN) ? sgr[r] : -1;
            }
        }
        // A-fragments straight from sorted bf16 rows (sequential; no conversion)
        bf16x8 af[2][2];
        #pragma unroll
        for (int rt = 0; rt < 2; ++rt) {
            int r = r0 + rt * 16 + lj;
            r = r < BN ? r : BN - 1;     // pad rows read row BN-1; excluded via sg=-1
            const char* rp = (const char*)xb + (size_t)r * 128 + lg * 16;
            af[rt][0] = *(const bf16x8*)(rp);
            af[rt][1] = *(const bf16x8*)(rp + 64);
        }

        f32x4 acc[2][4];
        #pragma unroll
        for (int a = 0; a < 2; ++a)
            #pragma unroll
            for (int b = 0; b < 4; ++b) acc[a][b] = f32x4{0.f, 0.f, 0.f, 0.f};
        // layer 1 (A from regs, B from LDS)
        #pragma unroll
        for (int kk = 0; kk < 2; ++kk) {
            const int kbyte = kk * 64 + lg * 16;
            bf16x8 bw[4];
            #pragma unroll
            for (int ct = 0; ct < 4; ++ct) {
                int row = ct * 16 + lj;
                bw[ct] = *(const bf16x8*)((char*)w1t + row * 128 + (kbyte ^ ((row & 7) << 4)));
            }
            #pragma unroll
            for (int rt = 0; rt < 2; ++rt)
                #pragma unroll
                for (int ct = 0; ct < 4; ++ct)
                    acc[rt][ct] = mfma16(af[rt][kk], bw[ct], acc[rt][ct]);
        }
        // epilogue 1: h1 -> own-wave LDS (A-layout rows 0..31, swizzled)
        #pragma unroll
        for (int rt = 0; rt < 2; ++rt) {
            #pragma unroll
            for (int ct = 0; ct < 4; ++ct) {
                f32x4 v = acc[rt][ct];
                #pragma unroll
                for (int rg = 0; rg < 4; ++rg) {
                    int row = rt * 16 + lg * 4 + rg;
                    int col = ct * 16 + lj;
                    float h = silu_f(v[rg] + bc1[ct]);
                    int off = row * 128 + ((2 * col) ^ ((row & 7) << 4));
                    *(unsigned short*)((char*)myx + off) = f2bf(h);
                }
                acc[rt][ct] = f32x4{0.f, 0.f, 0.f, 0.f};
            }
        }
        // layer 2 (A from own-wave LDS, B from LDS)
        #pragma unroll
        for (int kk = 0; kk < 2; ++kk) {
            const int kbyte = kk * 64 + lg * 16;
            bf16x8 bw[4];
            #pragma unroll
            for (int ct = 0; ct < 4; ++ct) {
                int row = ct * 16 + lj;
                bw[ct] = *(const bf16x8*)((char*)w2t + row * 128 + (kbyte ^ ((row & 7) << 4)));
            }
            #pragma unroll
            for (int rt = 0; rt < 2; ++rt) {
                int row = rt * 16 + lj;
                bf16x8 aw = *(const bf16x8*)((char*)myx + row * 128 + (kbyte ^ ((row & 7) << 4)));
                #pragma unroll
                for (int ct = 0; ct < 4; ++ct)
                    acc[rt][ct] = mfma16(aw, bw[ct], acc[rt][ct]);
            }
        }
        // epilogue 2: zT col-major (col stride 64B, swizzle (col&3)<<4), packed ushort4
        #pragma unroll
        for (int rt = 0; rt < 2; ++rt) {
            #pragma unroll
            for (int ct = 0; ct < 4; ++ct) {
                f32x4 v = acc[rt][ct];
                int col  = ct * 16 + lj;
                int row0 = rt * 16 + lg * 4;
                ushort4 pk;
                pk.x = f2bf(silu_f(v[0] + bc2[ct]));
                pk.y = f2bf(silu_f(v[1] + bc2[ct]));
                pk.z = f2bf(silu_f(v[2] + bc2[ct]));
                pk.w = f2bf(silu_f(v[3] + bc2[ct]));
                *(ushort4*)((char*)myx + col * 64 + ((2 * row0) ^ ((col & 3) << 4))) = pk;
            }
        }
        // segmented reduce: lane owns col; 8 rows per ds_read_b128 (4 blocks)
        {
            const int c2 = lane;
            const char* zT = (const char*)myx;
            float vsum = 0.0f;
            int curg = -2;
            #pragma unroll
            for (int blk = 0; blk < 4; ++blk) {
                u16x8 v = *(const u16x8*)(zT + c2 * 64 + ((16 * blk) ^ ((c2 & 3) << 4)));
                int4 ga = *(const int4*)(&sg_s[wv][blk * 8]);
                int4 gb = *(const int4*)(&sg_s[wv][blk * 8 + 4]);
                int gs[8] = {ga.x, ga.y, ga.z, ga.w, gb.x, gb.y, gb.z, gb.w};
                #pragma unroll
                for (int j = 0; j < 8; ++j) {
                    int g = gs[j];
                    if (g != curg) {
                        if (curg >= 0) atomicAdd(&gsum[curg * 64 + c2], vsum);
                        vsum = 0.0f;
                        curg = g;
                    }
                    vsum += bf2f(v[j]);
                }
            }
            if (curg >= 0) atomicAdd(&gsum[curg * 64 + c2], vsum);
        }
    }
}

// ============ fused phase 2+3: group head + sample | grid bar | broadcast ============
__global__ __launch_bounds__(256, 4) void k_phase23(
    const float* __restrict__ gsum, const int* __restrict__ counts,
    const float* __restrict__ W3, const float* __restrict__ b3,
    const float* __restrict__ wmu, const float* __restrict__ bmu,
    const float* __restrict__ wlv, const float* __restrict__ blv,
    const int* __restrict__ gl, float* __restrict__ out,
    float* __restrict__ taug, float* __restrict__ ltaug, int* __restrict__ bar)
{
    __shared__ __align__(16) float w3t[64 * 68];   // [j][k], stride 68 breaks write conflicts
    __shared__ float b3s[64], wmus[64], wlvs[64];
    const int t = threadIdx.x;

    if (blockIdx.x < KN / 256) {
        const int j = t & 63, qq = t >> 6;
        #pragma unroll
        for (int i = 0; i < 16; ++i) {
            int k = qq * 16 + i;
            w3t[j * 68 + k] = W3[k * 64 + j];   // coalesced read, transposed write
        }
        if (t < 64) { b3s[t] = b3[t]; wmus[t] = wmu[t]; wlvs[t] = wlv[t]; }
        __syncthreads();

        const int gid = blockIdx.x * 256 + t;
        const float inv = 1.0f / (float)counts[gid];
        float gf[64];
        #pragma unroll
        for (int i = 0; i < 16; ++i) {
            float4 v = *(const float4*)(gsum + (size_t)gid * 64 + i * 4);
            gf[i * 4 + 0] = v.x * inv; gf[i * 4 + 1] = v.y * inv;
            gf[i * 4 + 2] = v.z * inv; gf[i * 4 + 3] = v.w * inv;
        }
        float mu = b3s[0] * 0.0f + bmu[0], lv = blv[0];
        for (int jj = 0; jj < 64; ++jj) {
            float a = b3s[jj];
            const float4* wr = (const float4*)(w3t + jj * 68);
            #pragma unroll
            for (int k = 0; k < 16; ++k) {
                float4 wvv = wr[k];
                a += gf[k * 4 + 0] * wvv.x + gf[k * 4 + 1] * wvv.y
                   + gf[k * 4 + 2] * wvv.z + gf[k * 4 + 3] * wvv.w;
            }
            float h = silu_f(a);
            mu += h * wmus[jj];
            lv += h * wlvs[jj];
        }
        lv = fminf(fmaxf(lv, -10.0f), 4.0f);
        float sd  = __expf(0.5f * lv);
        float eps = jax_eps16384(gid);
        float lt  = mu + sd * eps;
        out[gid]      = mu;
        out[KN + gid] = lv;
        taug[gid]  = __expf(lt);
        ltaug[gid] = lt;
    }
    gridbar(bar, bar + 1, NBP);

    // broadcast per-group sample to reflections
    const int gtid = blockIdx.x * 256 + t;
    for (int i = gtid; i < BN / 4; i += NBP * 256) {
        int4 g = ((const int4*)gl)[i];
        float4 tv = make_float4(taug[g.x],  taug[g.y],  taug[g.z],  taug[g.w]);
        float4 lvv = make_float4(ltaug[g.x], ltaug[g.y], ltaug[g.z], ltaug[g.w]);
        ((float4*)(out + 2 * KN))[i]      = tv;
        ((float4*)(out + 2 * KN + BN))[i] = lvv;
    }
}

extern "C" void kernel_launch(void* const* d_in, const int* in_sizes, int n_in,
                              void* d_out, int out_size, void* d_ws, size_t ws_size,
                              hipStream_t stream)
{
    const float* x   = (const float*)d_in[0];
    const int*   gl  = (const int*)d_in[1];
    const float* W1  = (const float*)d_in[2];
    const float* b1  = (const float*)d_in[3];
    const float* W2  = (const float*)d_in[4];
    const float* b2  = (const float*)d_in[5];
    const float* W3  = (const float*)d_in[6];
    const float* b3  = (const float*)d_in[7];
    const float* wmu = (const float*)d_in[8];
    const float* bmu = (const float*)d_in[9];
    const float* wlv = (const float*)d_in[10];
    const float* blv = (const float*)d_in[11];
    float* out = (float*)d_out;

    // ws layout (bytes all 16-aligned): counts | bar(4) | cursor | sgr | gsum | taug | ltaug | xb
    int*   counts = (int*)d_ws;                        // KN
    int*   bar    = counts + KN;                       // 4 ints (bar0 pair, bar1 pair)
    int*   cursor = bar + 4;                           // KN
    int*   sgr    = cursor + KN;                       // BN
    float* gsum   = (float*)(sgr + BN);                // KN*64
    float* taug   = gsum + (size_t)KN * 64;            // KN
    float* ltaug  = taug + KN;                         // KN
    unsigned short* xb = (unsigned short*)(ltaug + KN);// BN*64 bf16 (128 MB)

    // one tiny memset: counts (64KB) + both barrier pairs (16B), contiguous
    hipMemsetAsync(counts, 0, (size_t)KN * sizeof(int) + 4 * sizeof(int), stream);

    k_sortchain<<<NBC, 256, 0, stream>>>(gl, x, counts, cursor, sgr, xb, (float4*)gsum, bar);
    k_phase1   <<<NB1, TPB1, 0, stream>>>(xb, sgr, W1, b1, W2, b2, gsum);
    k_phase23  <<<NBP, 256, 0, stream>>>(gsum, counts, W3, b3, wmu, bmu, wlv, blv,
                                         gl, out, taug, ltaug, bar + 2);
}

// Round 11
// 712.009 us; speedup vs baseline: 1.0932x; 1.0932x over previous
//
#include <hip/hip_runtime.h>

#define BN 1000000
#define KN 16384
#define TPB1 512
#define NW1 8
#define CHROWS 256                         // rows per block-chunk in phase1 (8 waves x 32)
#define NB1 512                            // phase1 persistent grid (2 blocks/CU)
#define NBC 512                            // sortchain grid (co-resident for gridbar)
#define NBP 512                            // phase23 grid (co-resident for gridbar)
#define NCHUNK ((BN + CHROWS - 1) / CHROWS)

typedef __bf16 bf16x8 __attribute__((ext_vector_type(8)));
typedef float  f32x4  __attribute__((ext_vector_type(4)));
typedef unsigned short u16x8 __attribute__((ext_vector_type(8)));

__device__ __forceinline__ unsigned short f2bf(float f) {
    return __builtin_bit_cast(unsigned short, (__bf16)f);   // HW v_cvt (RTNE)
}
__device__ __forceinline__ float bf2f(unsigned short b) {
    return (float)__builtin_bit_cast(__bf16, b);
}
__device__ __forceinline__ float silu_f(float v) {
    return v * __builtin_amdgcn_rcpf(1.0f + __expf(-v));
}
__device__ __forceinline__ f32x4 mfma16(bf16x8 a, bf16x8 b, f32x4 c) {
    return __builtin_amdgcn_mfma_f32_16x16x32_bf16(a, b, c, 0, 0, 0);
}

// ---- XLA ErfInv32 polynomial ----
__device__ __forceinline__ float erfinv_xla(float x) {
    float w = -log1pf(-x * x);
    float p;
    if (w < 5.0f) {
        w -= 2.5f;
        p = 2.81022636e-08f;
        p = fmaf(p, w, 3.43273939e-07f);
        p = fmaf(p, w, -3.5233877e-06f);
        p = fmaf(p, w, -4.39150654e-06f);
        p = fmaf(p, w, 0.00021858087f);
        p = fmaf(p, w, -0.00125372503f);
        p = fmaf(p, w, -0.00417768164f);
        p = fmaf(p, w, 0.246640727f);
        p = fmaf(p, w, 1.50140941f);
    } else {
        w = sqrtf(w) - 3.0f;
        p = -0.000200214257f;
        p = fmaf(p, w, 0.000100950558f);
        p = fmaf(p, w, 0.00134934322f);
        p = fmaf(p, w, -0.00367342844f);
        p = fmaf(p, w, 0.00573950773f);
        p = fmaf(p, w, -0.0076224613f);
        p = fmaf(p, w, 0.00943887047f);
        p = fmaf(p, w, 1.00167406f);
        p = fmaf(p, w, 2.83297682f);
    }
    return p * x;
}

// ---- jax.random.normal(key(42), (16384,)), threefry_partitionable: bits = out0^out1 ----
__device__ __forceinline__ float jax_eps16384(int gid) {
    const unsigned k0 = 0u, k1 = 42u, k2 = 0x1BD11BDAu ^ 0u ^ 42u;
    unsigned x0 = 0u + k0;
    unsigned x1 = (unsigned)gid + k1;
#define TF_RND(r) { x0 += x1; x1 = (x1 << (r)) | (x1 >> (32 - (r))); x1 ^= x0; }
    TF_RND(13) TF_RND(15) TF_RND(26) TF_RND(6)  x0 += k1; x1 += k2 + 1u;
    TF_RND(17) TF_RND(29) TF_RND(16) TF_RND(24) x0 += k2; x1 += k0 + 2u;
    TF_RND(13) TF_RND(15) TF_RND(26) TF_RND(6)  x0 += k0; x1 += k1 + 3u;
    TF_RND(17) TF_RND(29) TF_RND(16) TF_RND(24) x0 += k1; x1 += k2 + 4u;
    TF_RND(13) TF_RND(15) TF_RND(26) TF_RND(6)  x0 += k2; x1 += k0 + 5u;
#undef TF_RND
    unsigned bits = x0 ^ x1;
    float f = __uint_as_float((bits >> 9) | 0x3f800000u) - 1.0f;
    const float mn = -0.99999994f;
    float u = fmaxf(f * 2.0f + mn, mn);
    return 1.41421354f * erfinv_xla(u);
}

// ---- grid barrier (generation counter), agent-scope fenced — r8/r10-proven ----
__device__ __forceinline__ void gridbar(int* cnt, int* gen, int nblk) {
    __syncthreads();
    if (threadIdx.x == 0) {
        __threadfence();   // release
        int g = __hip_atomic_load(gen, __ATOMIC_ACQUIRE, __HIP_MEMORY_SCOPE_AGENT);
        int a = __hip_atomic_fetch_add(cnt, 1, __ATOMIC_ACQ_REL, __HIP_MEMORY_SCOPE_AGENT);
        if (a == nblk - 1) {
            __hip_atomic_store(cnt, 0, __ATOMIC_RELAXED, __HIP_MEMORY_SCOPE_AGENT);
            __hip_atomic_fetch_add(gen, 1, __ATOMIC_RELEASE, __HIP_MEMORY_SCOPE_AGENT);
        } else {
            while (__hip_atomic_load(gen, __ATOMIC_ACQUIRE, __HIP_MEMORY_SCOPE_AGENT) == g)
                __builtin_amdgcn_s_sleep(1);
        }
        __threadfence();   // acquire
    }
    __syncthreads();
}

// ============ fused sort chain: zero+histogram | scan | spk scatter (r9-style) ============
__global__ __launch_bounds__(256) void k_sortchain(
    const int* __restrict__ gl, int* __restrict__ counts, int* __restrict__ cursor,
    int2* __restrict__ spk, float4* __restrict__ gsumz, int* __restrict__ bar)
{
    const int t = threadIdx.x;
    const int gtid = blockIdx.x * 256 + t;
    const int NT = NBC * 256;

    // ---- phase B: zero gsum (visible to phase1 via kernel boundary) + histogram ----
    {
        const float4 z4 = make_float4(0.f, 0.f, 0.f, 0.f);
        for (int i = gtid; i < KN * 64 / 4; i += NT) gsumz[i] = z4;
        for (int i = gtid; i < BN / 4; i += NT) {
            int4 g = ((const int4*)gl)[i];
            atomicAdd(&counts[g.x], 1); atomicAdd(&counts[g.y], 1);
            atomicAdd(&counts[g.z], 1); atomicAdd(&counts[g.w], 1);
        }
    }
    gridbar(bar, bar + 1, NBC);

    // ---- phase C: exclusive scan (block 0; 256 threads x 64 counts) ----
    if (blockIdx.x == 0) {
        __shared__ int wt[4];
        const int lane = t & 63, wv = t >> 6;
        const int4* c4 = (const int4*)counts;
        int sum = 0;
        #pragma unroll
        for (int i = 0; i < 16; ++i) {
            int4 q = c4[t * 16 + i];
            sum += q.x + q.y + q.z + q.w;
        }
        int inc = sum;
        #pragma unroll
        for (int off = 1; off < 64; off <<= 1) {
            int v = __shfl_up(inc, off);
            if (lane >= off) inc += v;
        }
        if (lane == 63) wt[wv] = inc;
        __syncthreads();
        int wb = 0;
        #pragma unroll
        for (int w = 0; w < 4; ++w) wb += (w < wv) ? wt[w] : 0;
        int run = wb + inc - sum;
        int4* cu4 = (int4*)cursor;
        #pragma unroll
        for (int i = 0; i < 16; ++i) {
            int4 q = c4[t * 16 + i];
            int4 o;
            o.x = run; o.y = run + q.x; o.z = o.y + q.y; o.w = o.z + q.z;
            run = o.w + q.w;
            cu4[t * 16 + i] = o;
        }
    }
    gridbar(bar, bar + 1, NBC);

    // ---- phase D: scatter (row, group) int2 to sorted slots — r9-proven ----
    for (int i = gtid; i < BN / 4; i += NT) {
        int4 g = ((const int4*)gl)[i];
        int r = i * 4;
        int p0 = atomicAdd(&cursor[g.x], 1); spk[p0] = make_int2(r,     g.x);
        int p1 = atomicAdd(&cursor[g.y], 1); spk[p1] = make_int2(r + 1, g.y);
        int p2 = atomicAdd(&cursor[g.z], 1); spk[p2] = make_int2(r + 2, g.z);
        int p3 = atomicAdd(&cursor[g.w], 1); spk[p3] = make_int2(r + 3, g.w);
    }
}

// ============ phase 1: persistent MLP on sorted rows + segmented reduce (r9 verbatim) ======
__global__ __launch_bounds__(TPB1, 4) void k_phase1(
    const float* __restrict__ x, const int2* __restrict__ spk,
    const float* __restrict__ W1, const float* __restrict__ b1,
    const float* __restrict__ W2, const float* __restrict__ b2,
    float* __restrict__ gsum)
{
    __shared__ __align__(16) unsigned short w1t[64 * 64];    // [j][k] bf16, swizzled
    __shared__ __align__(16) unsigned short w2t[64 * 64];
    __shared__ __align__(16) unsigned short xh[NW1][32 * 64]; // per-wave: h1 then zT
    __shared__ float b1s[64], b2s[64];
    __shared__ int sg_s[NW1][32];

    const int t = threadIdx.x;
    const int wv = t >> 6, lane = t & 63;
    const int lj = lane & 15, lg = lane >> 4;

    // ---- stage W1^T, W2^T (bf16, swizzled) — once per block ----
    {
        const float4* W1v = (const float4*)W1;
        const float4* W2v = (const float4*)W2;
        #pragma unroll
        for (int i = 0; i < 2; ++i) {
            int e4 = i * TPB1 + t;
            int k  = e4 >> 4;
            int j0 = (e4 & 15) * 4;
            float4 a = W1v[e4];
            float4 b = W2v[e4];
            float av[4] = {a.x, a.y, a.z, a.w};
            float bv[4] = {b.x, b.y, b.z, b.w};
            #pragma unroll
            for (int c = 0; c < 4; ++c) {
                int j = j0 + c;
                int off = j * 128 + ((2 * k) ^ ((j & 7) << 4));
                *(unsigned short*)((char*)w1t + off) = f2bf(av[c]);
                *(unsigned short*)((char*)w2t + off) = f2bf(bv[c]);
            }
        }
        if (t < 64) { b1s[t] = b1[t]; b2s[t] = b2[t]; }
    }
    __syncthreads();   // the ONLY block barrier (startup)

    float bc1[4], bc2[4];
    #pragma unroll
    for (int ct = 0; ct < 4; ++ct) { bc1[ct] = b1s[ct * 16 + lj]; bc2[ct] = b2s[ct * 16 + lj]; }

    unsigned short* myx = &xh[wv][0];
    int2 rsA[2], rsB[2];

    auto load_spk = [&](int c, int2 (&dst)[2]) {
        int cc = c < NCHUNK - 1 ? c : NCHUNK - 1;
        #pragma unroll
        for (int rt = 0; rt < 2; ++rt) {
            int r = cc * CHROWS + wv * 32 + rt * 16 + lj;
            dst[rt] = spk[r < BN ? r : BN - 1];
        }
    };

    auto iter = [&](int2 (&CUR)[2], int2 (&NXT)[2], int c) {
        float4 xr[2][4];
        #pragma unroll
        for (int rt = 0; rt < 2; ++rt) {
            const float* xp = x + (size_t)CUR[rt].x * 64 + lg * 8;
            xr[rt][0] = *(const float4*)(xp);
            xr[rt][1] = *(const float4*)(xp + 4);
            xr[rt][2] = *(const float4*)(xp + 32);
            xr[rt][3] = *(const float4*)(xp + 36);
        }
        load_spk(c + NB1, NXT);
        if (lg == 0) {
            #pragma unroll
            for (int rt = 0; rt < 2; ++rt) {
                int r = c * CHROWS + wv * 32 + rt * 16 + lj;
                sg_s[wv][rt * 16 + lj] = (r < BN) ? CUR[rt].y : -1;
            }
        }
        bf16x8 af[2][2];
        #pragma unroll
        for (int rt = 0; rt < 2; ++rt)
            #pragma unroll
            for (int kk = 0; kk < 2; ++kk) {
                float4 a = xr[rt][kk * 2], b = xr[rt][kk * 2 + 1];
                u16x8 u;
                u[0] = f2bf(a.x); u[1] = f2bf(a.y); u[2] = f2bf(a.z); u[3] = f2bf(a.w);
                u[4] = f2bf(b.x); u[5] = f2bf(b.y); u[6] = f2bf(b.z); u[7] = f2bf(b.w);
                af[rt][kk] = __builtin_bit_cast(bf16x8, u);
            }

        f32x4 acc[2][4];
        #pragma unroll
        for (int a = 0; a < 2; ++a)
            #pragma unroll
            for (int b = 0; b < 4; ++b) acc[a][b] = f32x4{0.f, 0.f, 0.f, 0.f};
        #pragma unroll
        for (int kk = 0; kk < 2; ++kk) {
            const int kbyte = kk * 64 + lg * 16;
            bf16x8 bw[4];
            #pragma unroll
            for (int ct = 0; ct < 4; ++ct) {
                int row = ct * 16 + lj;
                bw[ct] = *(const bf16x8*)((char*)w1t + row * 128 + (kbyte ^ ((row & 7) << 4)));
            }
            #pragma unroll
            for (int rt = 0; rt < 2; ++rt)
                #pragma unroll
                for (int ct = 0; ct < 4; ++ct)
                    acc[rt][ct] = mfma16(af[rt][kk], bw[ct], acc[rt][ct]);
        }
        #pragma unroll
        for (int rt = 0; rt < 2; ++rt) {
            #pragma unroll
            for (int ct = 0; ct < 4; ++ct) {
                f32x4 v = acc[rt][ct];
                #pragma unroll
                for (int rg = 0; rg < 4; ++rg) {
                    int row = rt * 16 + lg * 4 + rg;
                    int col = ct * 16 + lj;
                    float h = silu_f(v[rg] + bc1[ct]);
                    int off = row * 128 + ((2 * col) ^ ((row & 7) << 4));
                    *(unsigned short*)((char*)myx + off) = f2bf(h);
                }
                acc[rt][ct] = f32x4{0.f, 0.f, 0.f, 0.f};
            }
        }
        #pragma unroll
        for (int kk = 0; kk < 2; ++kk) {
            const int kbyte = kk * 64 + lg * 16;
            bf16x8 bw[4];
            #pragma unroll
            for (int ct = 0; ct < 4; ++ct) {
                int row = ct * 16 + lj;
                bw[ct] = *(const bf16x8*)((char*)w2t + row * 128 + (kbyte ^ ((row & 7) << 4)));
            }
            #pragma unroll
            for (int rt = 0; rt < 2; ++rt) {
                int row = rt * 16 + lj;
                bf16x8 aw = *(const bf16x8*)((char*)myx + row * 128 + (kbyte ^ ((row & 7) << 4)));
                #pragma unroll
                for (int ct = 0; ct < 4; ++ct)
                    acc[rt][ct] = mfma16(aw, bw[ct], acc[rt][ct]);
            }
        }
        #pragma unroll
        for (int rt = 0; rt < 2; ++rt) {
            #pragma unroll
            for (int ct = 0; ct < 4; ++ct) {
                f32x4 v = acc[rt][ct];
                int col  = ct * 16 + lj;
                int row0 = rt * 16 + lg * 4;
                ushort4 pk;
                pk.x = f2bf(silu_f(v[0] + bc2[ct]));
                pk.y = f2bf(silu_f(v[1] + bc2[ct]));
                pk.z = f2bf(silu_f(v[2] + bc2[ct]));
                pk.w = f2bf(silu_f(v[3] + bc2[ct]));
                *(ushort4*)((char*)myx + col * 64 + ((2 * row0) ^ ((col & 3) << 4))) = pk;
            }
        }
        {
            const int c2 = lane;
            const char* zT = (const char*)myx;
            float vsum = 0.0f;
            int curg = -2;
            #pragma unroll
            for (int blk = 0; blk < 4; ++blk) {
                u16x8 v = *(const u16x8*)(zT + c2 * 64 + ((16 * blk) ^ ((c2 & 3) << 4)));
                int4 ga = *(const int4*)(&sg_s[wv][blk * 8]);
                int4 gb = *(const int4*)(&sg_s[wv][blk * 8 + 4]);
                int gs[8] = {ga.x, ga.y, ga.z, ga.w, gb.x, gb.y, gb.z, gb.w};
                #pragma unroll
                for (int j = 0; j < 8; ++j) {
                    int g = gs[j];
                    if (g != curg) {
                        if (curg >= 0) atomicAdd(&gsum[curg * 64 + c2], vsum);
                        vsum = 0.0f;
                        curg = g;
                    }
                    vsum += bf2f(v[j]);
                }
            }
            if (curg >= 0) atomicAdd(&gsum[curg * 64 + c2], vsum);
        }
    };

    int c = blockIdx.x;
    load_spk(c, rsA);
    while (true) {
        iter(rsA, rsB, c); c += NB1; if (c >= NCHUNK) break;
        iter(rsB, rsA, c); c += NB1; if (c >= NCHUNK) break;
    }
}

// ============ fused phase 2+3: group head + sample | grid bar | broadcast ============
__global__ __launch_bounds__(256, 4) void k_phase23(
    const float* __restrict__ gsum, const int* __restrict__ counts,
    const float* __restrict__ W3, const float* __restrict__ b3,
    const float* __restrict__ wmu, const float* __restrict__ bmu,
    const float* __restrict__ wlv, const float* __restrict__ blv,
    const int* __restrict__ gl, float* __restrict__ out,
    float* __restrict__ taug, float* __restrict__ ltaug, int* __restrict__ bar)
{
    __shared__ __align__(16) float w3t[64 * 68];   // [j][k], stride 68 breaks write conflicts
    __shared__ float b3s[64], wmus[64], wlvs[64];
    const int t = threadIdx.x;

    if (blockIdx.x < KN / 256) {
        const int j = t & 63, qq = t >> 6;
        #pragma unroll
        for (int i = 0; i < 16; ++i) {
            int k = qq * 16 + i;
            w3t[j * 68 + k] = W3[k * 64 + j];   // coalesced read, transposed write
        }
        if (t < 64) { b3s[t] = b3[t]; wmus[t] = wmu[t]; wlvs[t] = wlv[t]; }
        __syncthreads();

        const int gid = blockIdx.x * 256 + t;
        const float inv = 1.0f / (float)counts[gid];
        float gf[64];
        #pragma unroll
        for (int i = 0; i < 16; ++i) {
            float4 v = *(const float4*)(gsum + (size_t)gid * 64 + i * 4);
            gf[i * 4 + 0] = v.x * inv; gf[i * 4 + 1] = v.y * inv;
            gf[i * 4 + 2] = v.z * inv; gf[i * 4 + 3] = v.w * inv;
        }
        float mu = bmu[0], lv = blv[0];
        for (int jj = 0; jj < 64; ++jj) {
            float a = b3s[jj];
            const float4* wr = (const float4*)(w3t + jj * 68);
            #pragma unroll
            for (int k = 0; k < 16; ++k) {
                float4 wvv = wr[k];
                a += gf[k * 4 + 0] * wvv.x + gf[k * 4 + 1] * wvv.y
                   + gf[k * 4 + 2] * wvv.z + gf[k * 4 + 3] * wvv.w;
            }
            float h = silu_f(a);
            mu += h * wmus[jj];
            lv += h * wlvs[jj];
        }
        lv = fminf(fmaxf(lv, -10.0f), 4.0f);
        float sd  = __expf(0.5f * lv);
        float eps = jax_eps16384(gid);
        float lt  = mu + sd * eps;
        out[gid]      = mu;
        out[KN + gid] = lv;
        taug[gid]  = __expf(lt);
        ltaug[gid] = lt;
    }
    gridbar(bar, bar + 1, NBP);

    // broadcast per-group sample to reflections
    const int gtid = blockIdx.x * 256 + t;
    for (int i = gtid; i < BN / 4; i += NBP * 256) {
        int4 g = ((const int4*)gl)[i];
        float4 tv  = make_float4(taug[g.x],  taug[g.y],  taug[g.z],  taug[g.w]);
        float4 lvv = make_float4(ltaug[g.x], ltaug[g.y], ltaug[g.z], ltaug[g.w]);
        ((float4*)(out + 2 * KN))[i]      = tv;
        ((float4*)(out + 2 * KN + BN))[i] = lvv;
    }
}

extern "C" void kernel_launch(void* const* d_in, const int* in_sizes, int n_in,
                              void* d_out, int out_size, void* d_ws, size_t ws_size,
                              hipStream_t stream)
{
    const float* x   = (const float*)d_in[0];
    const int*   gl  = (const int*)d_in[1];
    const float* W1  = (const float*)d_in[2];
    const float* b1  = (const float*)d_in[3];
    const float* W2  = (const float*)d_in[4];
    const float* b2  = (const float*)d_in[5];
    const float* W3  = (const float*)d_in[6];
    const float* b3  = (const float*)d_in[7];
    const float* wmu = (const float*)d_in[8];
    const float* bmu = (const float*)d_in[9];
    const float* wlv = (const float*)d_in[10];
    const float* blv = (const float*)d_in[11];
    float* out = (float*)d_out;

    // ws layout — every segment 256B-aligned (r10 lesson: misalignment => RMW amplification)
    int*   counts = (int*)d_ws;                        // KN ints (64KB)
    int*   bar    = counts + KN;                       // 64 ints (256B); [0,1]=chain, [8,9]=p23
    int*   cursor = bar + 64;                          // KN ints
    float* gsum   = (float*)(cursor + KN);             // KN*64 f32 (4MB)
    float* taug   = gsum + (size_t)KN * 64;            // KN
    float* ltaug  = taug + KN;                         // KN
    int2*  spk    = (int2*)(ltaug + KN);               // BN int2 (8MB)

    // one memset: counts + bar (contiguous)
    hipMemsetAsync(counts, 0, (size_t)KN * sizeof(int) + 256, stream);

    k_sortchain<<<NBC, 256, 0, stream>>>(gl, counts, cursor, spk, (float4*)gsum, bar);
    k_phase1   <<<NB1, TPB1, 0, stream>>>(x, spk, W1, b1, W2, b2, gsum);
    k_phase23  <<<NBP, 256, 0, stream>>>(gsum, counts, W3, b3, wmu, bmu, wlv, blv,
                                         gl, out, taug, ltaug, bar + 8);
}

// Round 12
// 275.915 us; speedup vs baseline: 2.8211x; 2.5805x over previous
//
#include <hip/hip_runtime.h>

#define BN 1000000
#define KN 16384
#define TPB1 512
#define NW1 8
#define CHROWS 256                          // rows per block-chunk (8 waves x 32)
#define NB1 512                             // phase1 persistent grid (2 blocks/CU)
#define NCHUNK ((BN + CHROWS - 1) / CHROWS) // 3907

typedef __bf16 bf16x8 __attribute__((ext_vector_type(8)));
typedef float  f32x4  __attribute__((ext_vector_type(4)));
typedef unsigned short u16x8 __attribute__((ext_vector_type(8)));

__device__ __forceinline__ unsigned short f2bf(float f) {
    return __builtin_bit_cast(unsigned short, (__bf16)f);   // HW v_cvt (RTNE)
}
__device__ __forceinline__ float bf2f(unsigned short b) {
    return (float)__builtin_bit_cast(__bf16, b);
}
__device__ __forceinline__ float silu_f(float v) {
    return v * __builtin_amdgcn_rcpf(1.0f + __expf(-v));
}
__device__ __forceinline__ f32x4 mfma16(bf16x8 a, bf16x8 b, f32x4 c) {
    return __builtin_amdgcn_mfma_f32_16x16x32_bf16(a, b, c, 0, 0, 0);
}

// ---- XLA ErfInv32 polynomial ----
__device__ __forceinline__ float erfinv_xla(float x) {
    float w = -log1pf(-x * x);
    float p;
    if (w < 5.0f) {
        w -= 2.5f;
        p = 2.81022636e-08f;
        p = fmaf(p, w, 3.43273939e-07f);
        p = fmaf(p, w, -3.5233877e-06f);
        p = fmaf(p, w, -4.39150654e-06f);
        p = fmaf(p, w, 0.00021858087f);
        p = fmaf(p, w, -0.00125372503f);
        p = fmaf(p, w, -0.00417768164f);
        p = fmaf(p, w, 0.246640727f);
        p = fmaf(p, w, 1.50140941f);
    } else {
        w = sqrtf(w) - 3.0f;
        p = -0.000200214257f;
        p = fmaf(p, w, 0.000100950558f);
        p = fmaf(p, w, 0.00134934322f);
        p = fmaf(p, w, -0.00367342844f);
        p = fmaf(p, w, 0.00573950773f);
        p = fmaf(p, w, -0.0076224613f);
        p = fmaf(p, w, 0.00943887047f);
        p = fmaf(p, w, 1.00167406f);
        p = fmaf(p, w, 2.83297682f);
    }
    return p * x;
}

// ---- jax.random.normal(key(42), (16384,)), threefry_partitionable: bits = out0^out1 ----
__device__ __forceinline__ float jax_eps16384(int gid) {
    const unsigned k0 = 0u, k1 = 42u, k2 = 0x1BD11BDAu ^ 0u ^ 42u;
    unsigned x0 = 0u + k0;
    unsigned x1 = (unsigned)gid + k1;
#define TF_RND(r) { x0 += x1; x1 = (x1 << (r)) | (x1 >> (32 - (r))); x1 ^= x0; }
    TF_RND(13) TF_RND(15) TF_RND(26) TF_RND(6)  x0 += k1; x1 += k2 + 1u;
    TF_RND(17) TF_RND(29) TF_RND(16) TF_RND(24) x0 += k2; x1 += k0 + 2u;
    TF_RND(13) TF_RND(15) TF_RND(26) TF_RND(6)  x0 += k0; x1 += k1 + 3u;
    TF_RND(17) TF_RND(29) TF_RND(16) TF_RND(24) x0 += k1; x1 += k2 + 4u;
    TF_RND(13) TF_RND(15) TF_RND(26) TF_RND(6)  x0 += k2; x1 += k0 + 5u;
#undef TF_RND
    unsigned bits = x0 ^ x1;
    float f = __uint_as_float((bits >> 9) | 0x3f800000u) - 1.0f;
    const float mn = -0.99999994f;
    float u = fmaxf(f * 2.0f + mn, mn);
    return 1.41421354f * erfinv_xla(u);
}

// ============ counting sort: histogram(+gsum zero), shuffle-scan, scatter (r9) ============
__global__ __launch_bounds__(256) void k_count(const int* __restrict__ gl,
                                               int* __restrict__ counts,
                                               float4* __restrict__ gz) {
    int i = blockIdx.x * 256 + threadIdx.x;
    const float4 z4 = make_float4(0.f, 0.f, 0.f, 0.f);
    for (int j = i; j < KN * 64 / 4; j += 250112) gz[j] = z4;   // fold gsum memset in
    if (i < BN / 4) {
        int4 g = ((const int4*)gl)[i];
        atomicAdd(&counts[g.x], 1); atomicAdd(&counts[g.y], 1);
        atomicAdd(&counts[g.z], 1); atomicAdd(&counts[g.w], 1);
    }
}

__global__ __launch_bounds__(1024) void k_scan(const int* __restrict__ counts, int* __restrict__ cursor) {
    __shared__ int wtot[16];
    const int t = threadIdx.x, lane = t & 63, wv = t >> 6;
    const int4* c4 = (const int4*)counts;
    int4 q0 = c4[t * 4], q1 = c4[t * 4 + 1], q2 = c4[t * 4 + 2], q3 = c4[t * 4 + 3];
    int c[16] = {q0.x, q0.y, q0.z, q0.w, q1.x, q1.y, q1.z, q1.w,
                 q2.x, q2.y, q2.z, q2.w, q3.x, q3.y, q3.z, q3.w};
    int loc[16], s = 0;
    #pragma unroll
    for (int i = 0; i < 16; ++i) { loc[i] = s; s += c[i]; }
    const int own = s;
    #pragma unroll
    for (int off = 1; off < 64; off <<= 1) {      // inclusive wave scan
        int v = __shfl_up(s, off);
        if (lane >= off) s += v;
    }
    if (lane == 63) wtot[wv] = s;
    __syncthreads();
    int wbase = 0;
    #pragma unroll
    for (int w = 0; w < 16; ++w) wbase += (w < wv) ? wtot[w] : 0;
    const int ebase = wbase + s - own;
    int o[16];
    #pragma unroll
    for (int i = 0; i < 16; ++i) o[i] = ebase + loc[i];
    int4* o4 = (int4*)cursor;
    o4[t * 4]     = make_int4(o[0],  o[1],  o[2],  o[3]);
    o4[t * 4 + 1] = make_int4(o[4],  o[5],  o[6],  o[7]);
    o4[t * 4 + 2] = make_int4(o[8],  o[9],  o[10], o[11]);
    o4[t * 4 + 3] = make_int4(o[12], o[13], o[14], o[15]);
}

__global__ __launch_bounds__(256) void k_scatter(const int* __restrict__ gl, int* __restrict__ cursor,
                                                 int2* __restrict__ spk) {
    int i = blockIdx.x * 256 + threadIdx.x;
    if (i < BN / 4) {
        int4 g = ((const int4*)gl)[i];
        int r = i * 4;
        int p0 = atomicAdd(&cursor[g.x], 1); spk[p0] = make_int2(r,     g.x);
        int p1 = atomicAdd(&cursor[g.y], 1); spk[p1] = make_int2(r + 1, g.y);
        int p2 = atomicAdd(&cursor[g.z], 1); spk[p2] = make_int2(r + 2, g.z);
        int p3 = atomicAdd(&cursor[g.w], 1); spk[p3] = make_int2(r + 3, g.w);
    }
}

// ============ phase 1: r9 + sched_barrier-pinned within-wave gather prefetch ============
__global__ __launch_bounds__(TPB1, 4) void k_phase1(
    const float* __restrict__ x, const int2* __restrict__ spk,
    const float* __restrict__ W1, const float* __restrict__ b1,
    const float* __restrict__ W2, const float* __restrict__ b2,
    float* __restrict__ gsum)
{
    __shared__ __align__(16) unsigned short w1t[64 * 64];    // [j][k] bf16, swizzled
    __shared__ __align__(16) unsigned short w2t[64 * 64];
    __shared__ __align__(16) unsigned short xh[NW1][32 * 64]; // per-wave: h1 then zT
    __shared__ float b1s[64], b2s[64];
    __shared__ int sg_s[NW1][32];

    const int t = threadIdx.x;
    const int wv = t >> 6, lane = t & 63;
    const int lj = lane & 15, lg = lane >> 4;

    // ---- stage W1^T, W2^T (bf16, swizzled) — once per block ----
    {
        const float4* W1v = (const float4*)W1;
        const float4* W2v = (const float4*)W2;
        #pragma unroll
        for (int i = 0; i < 2; ++i) {
            int e4 = i * TPB1 + t;
            int k  = e4 >> 4;
            int j0 = (e4 & 15) * 4;
            float4 a = W1v[e4];
            float4 b = W2v[e4];
            float av[4] = {a.x, a.y, a.z, a.w};
            float bv[4] = {b.x, b.y, b.z, b.w};
            #pragma unroll
            for (int c = 0; c < 4; ++c) {
                int j = j0 + c;
                int off = j * 128 + ((2 * k) ^ ((j & 7) << 4));
                *(unsigned short*)((char*)w1t + off) = f2bf(av[c]);
                *(unsigned short*)((char*)w2t + off) = f2bf(bv[c]);
            }
        }
        if (t < 64) { b1s[t] = b1[t]; b2s[t] = b2[t]; }
    }
    __syncthreads();   // the ONLY block barrier (startup)

    unsigned short* myx = &xh[wv][0];
    int2   rsA[2], rsB[2];
    float4 xr[2][4];      // single-buffered gather payload; refilled for chunk c+NB1 pre-compute

    auto load_spk = [&](int c, int2 (&dst)[2]) {
        int cc = c < NCHUNK - 1 ? c : NCHUNK - 1;
        #pragma unroll
        for (int rt = 0; rt < 2; ++rt) {
            int r = cc * CHROWS + wv * 32 + rt * 16 + lj;
            dst[rt] = spk[r < BN ? r : BN - 1];
        }
    };
    auto load_x = [&](const int2 (&src)[2]) {
        #pragma unroll
        for (int rt = 0; rt < 2; ++rt) {
            const float* xp = x + (size_t)src[rt].x * 64 + lg * 8;
            xr[rt][0] = *(const float4*)(xp);
            xr[rt][1] = *(const float4*)(xp + 4);
            xr[rt][2] = *(const float4*)(xp + 32);
            xr[rt][3] = *(const float4*)(xp + 36);
        }
    };

    // iter: xr holds chunk c's rows (in flight); CUR holds spk(c); NXT holds spk(c+NB1).
    auto iter = [&](int2 (&CUR)[2], int2 (&NXT)[2], int c) {
        // 1. convert xr -> af (compiler-inserted vmcnt wait lands here)
        bf16x8 af[2][2];
        #pragma unroll
        for (int rt = 0; rt < 2; ++rt)
            #pragma unroll
            for (int kk = 0; kk < 2; ++kk) {
                float4 a = xr[rt][kk * 2], b = xr[rt][kk * 2 + 1];
                u16x8 u;
                u[0] = f2bf(a.x); u[1] = f2bf(a.y); u[2] = f2bf(a.z); u[3] = f2bf(a.w);
                u[4] = f2bf(b.x); u[5] = f2bf(b.y); u[6] = f2bf(b.z); u[7] = f2bf(b.w);
                af[rt][kk] = __builtin_bit_cast(bf16x8, u);
            }
        // 2. sg for chunk c (wave-private)
        if (lg == 0) {
            #pragma unroll
            for (int rt = 0; rt < 2; ++rt) {
                int r = c * CHROWS + wv * 32 + rt * 16 + lj;
                sg_s[wv][rt * 16 + lj] = (r < BN) ? CUR[rt].y : -1;
            }
        }
        // 3. PINNED PREFETCH: issue gathers for chunk c+NB1 (xr dead -> refill) and
        //    spk for c+2*NB1 into CUR (dead). sched_barrier fences keep these issues
        //    ABOVE the compute so they fly under the MFMA/epilogue/reduce block.
        __builtin_amdgcn_sched_barrier(0);
        load_x(NXT);
        load_spk(c + 2 * NB1, CUR);
        __builtin_amdgcn_sched_barrier(0);

        // 4. compute chunk c from af
        f32x4 acc[2][4];
        #pragma unroll
        for (int a = 0; a < 2; ++a)
            #pragma unroll
            for (int b = 0; b < 4; ++b) acc[a][b] = f32x4{0.f, 0.f, 0.f, 0.f};
        // layer 1 (A from regs, B from LDS; bw in pairs to cap register pressure)
        #pragma unroll
        for (int kk = 0; kk < 2; ++kk) {
            const int kbyte = kk * 64 + lg * 16;
            #pragma unroll
            for (int cth = 0; cth < 2; ++cth) {
                int r0 = (cth * 2) * 16 + lj, r1 = (cth * 2 + 1) * 16 + lj;
                bf16x8 bw0 = *(const bf16x8*)((char*)w1t + r0 * 128 + (kbyte ^ ((r0 & 7) << 4)));
                bf16x8 bw1 = *(const bf16x8*)((char*)w1t + r1 * 128 + (kbyte ^ ((r1 & 7) << 4)));
                #pragma unroll
                for (int rt = 0; rt < 2; ++rt) {
                    acc[rt][cth * 2]     = mfma16(af[rt][kk], bw0, acc[rt][cth * 2]);
                    acc[rt][cth * 2 + 1] = mfma16(af[rt][kk], bw1, acc[rt][cth * 2 + 1]);
                }
            }
        }
        // epilogue 1: h1 -> own-wave LDS (A-layout rows 0..31, swizzled); bias from LDS
        #pragma unroll
        for (int rt = 0; rt < 2; ++rt) {
            #pragma unroll
            for (int ct = 0; ct < 4; ++ct) {
                float bc = b1s[ct * 16 + lj];
                f32x4 v = acc[rt][ct];
                #pragma unroll
                for (int rg = 0; rg < 4; ++rg) {
                    int row = rt * 16 + lg * 4 + rg;
                    int col = ct * 16 + lj;
                    float h = silu_f(v[rg] + bc);
                    int off = row * 128 + ((2 * col) ^ ((row & 7) << 4));
                    *(unsigned short*)((char*)myx + off) = f2bf(h);
                }
                acc[rt][ct] = f32x4{0.f, 0.f, 0.f, 0.f};
            }
        }
        // layer 2 (A from own-wave LDS, B from LDS)
        #pragma unroll
        for (int kk = 0; kk < 2; ++kk) {
            const int kbyte = kk * 64 + lg * 16;
            #pragma unroll
            for (int cth = 0; cth < 2; ++cth) {
                int r0 = (cth * 2) * 16 + lj, r1 = (cth * 2 + 1) * 16 + lj;
                bf16x8 bw0 = *(const bf16x8*)((char*)w2t + r0 * 128 + (kbyte ^ ((r0 & 7) << 4)));
                bf16x8 bw1 = *(const bf16x8*)((char*)w2t + r1 * 128 + (kbyte ^ ((r1 & 7) << 4)));
                #pragma unroll
                for (int rt = 0; rt < 2; ++rt) {
                    int row = rt * 16 + lj;
                    bf16x8 aw = *(const bf16x8*)((char*)myx + row * 128 + (kbyte ^ ((row & 7) << 4)));
                    acc[rt][cth * 2]     = mfma16(aw, bw0, acc[rt][cth * 2]);
                    acc[rt][cth * 2 + 1] = mfma16(aw, bw1, acc[rt][cth * 2 + 1]);
                }
            }
        }
        // epilogue 2: zT col-major (col stride 64B, swizzle (col&3)<<4), packed ushort4
        #pragma unroll
        for (int rt = 0; rt < 2; ++rt) {
            #pragma unroll
            for (int ct = 0; ct < 4; ++ct) {
                float bc = b2s[ct * 16 + lj];
                f32x4 v = acc[rt][ct];
                int col  = ct * 16 + lj;
                int row0 = rt * 16 + lg * 4;
                ushort4 pk;
                pk.x = f2bf(silu_f(v[0] + bc));
                pk.y = f2bf(silu_f(v[1] + bc));
                pk.z = f2bf(silu_f(v[2] + bc));
                pk.w = f2bf(silu_f(v[3] + bc));
                *(ushort4*)((char*)myx + col * 64 + ((2 * row0) ^ ((col & 3) << 4))) = pk;
            }
        }
        // segmented reduce: lane owns col; 8 rows per ds_read_b128 (4 blocks)
        {
            const int c2 = lane;
            const char* zT = (const char*)myx;
            float vsum = 0.0f;
            int curg = -2;
            #pragma unroll
            for (int blk = 0; blk < 4; ++blk) {
                u16x8 v = *(const u16x8*)(zT + c2 * 64 + ((16 * blk) ^ ((c2 & 3) << 4)));
                int4 ga = *(const int4*)(&sg_s[wv][blk * 8]);
                int4 gb = *(const int4*)(&sg_s[wv][blk * 8 + 4]);
                int gs[8] = {ga.x, ga.y, ga.z, ga.w, gb.x, gb.y, gb.z, gb.w};
                #pragma unroll
                for (int j = 0; j < 8; ++j) {
                    int g = gs[j];
                    if (g != curg) {
                        if (curg >= 0) atomicAdd(&gsum[curg * 64 + c2], vsum);
                        vsum = 0.0f;
                        curg = g;
                    }
                    vsum += bf2f(v[j]);
                }
            }
            if (curg >= 0) atomicAdd(&gsum[curg * 64 + c2], vsum);
        }
    };

    // ---- prologue + ping-pong loop ----
    int c = blockIdx.x;
    load_spk(c, rsA);          // spk(c) in flight
    load_x(rsA);               // waits rsA; gathers for chunk c in flight
    load_spk(c + NB1, rsB);    // spk(c+NB1) in flight
    while (true) {
        iter(rsA, rsB, c); c += NB1; if (c >= NCHUNK) break;
        iter(rsB, rsA, c); c += NB1; if (c >= NCHUNK) break;
    }
}

// ============ phase 2: group head + reparam sample (r9 verbatim: 64-thr, no VGPR cap) ======
__global__ __launch_bounds__(64) void k_phase2(
    const float* __restrict__ gsum, const int* __restrict__ counts,
    const float* __restrict__ W3, const float* __restrict__ b3,
    const float* __restrict__ wmu, const float* __restrict__ bmu,
    const float* __restrict__ wlv, const float* __restrict__ blv,
    float* __restrict__ out, float* __restrict__ taug, float* __restrict__ ltaug)
{
    __shared__ __align__(16) float w3t[64 * 64];   // [j][k]
    __shared__ float b3s[64], wmus[64], wlvs[64];
    const int t = threadIdx.x;
    for (int i = 0; i < 64; ++i) w3t[t * 64 + i] = W3[i * 64 + t];
    b3s[t] = b3[t]; wmus[t] = wmu[t]; wlvs[t] = wlv[t];
    __syncthreads();

    const int gid = blockIdx.x * 64 + t;
    const float inv = 1.0f / (float)counts[gid];
    float gf[64];
    #pragma unroll
    for (int i = 0; i < 16; ++i) {
        float4 v = *(const float4*)(gsum + (size_t)gid * 64 + i * 4);
        gf[i * 4 + 0] = v.x * inv; gf[i * 4 + 1] = v.y * inv;
        gf[i * 4 + 2] = v.z * inv; gf[i * 4 + 3] = v.w * inv;
    }
    float mu = bmu[0], lv = blv[0];
    for (int j = 0; j < 64; ++j) {
        float a = b3s[j];
        const float4* wr = (const float4*)(w3t + j * 64);
        #pragma unroll
        for (int k = 0; k < 16; ++k) {
            float4 wv = wr[k];
            a += gf[k * 4 + 0] * wv.x + gf[k * 4 + 1] * wv.y
               + gf[k * 4 + 2] * wv.z + gf[k * 4 + 3] * wv.w;
        }
        float h = silu_f(a);
        mu += h * wmus[j];
        lv += h * wlvs[j];
    }
    lv = fminf(fmaxf(lv, -10.0f), 4.0f);
    float sd  = __expf(0.5f * lv);
    float eps = jax_eps16384(gid);
    float lt  = mu + sd * eps;
    out[gid]      = mu;
    out[KN + gid] = lv;
    taug[gid]  = __expf(lt);
    ltaug[gid] = lt;
}

// ============ phase 3: broadcast per-group sample to reflections (r9 verbatim) ============
__global__ __launch_bounds__(256) void k_phase3(
    const int* __restrict__ gl, const float* __restrict__ taug,
    const float* __restrict__ ltaug, float* __restrict__ out)
{
    int i = blockIdx.x * 256 + threadIdx.x;
    if (i < BN / 4) {
        int4 g = ((const int4*)gl)[i];
        float4 tv = make_float4(taug[g.x],  taug[g.y],  taug[g.z],  taug[g.w]);
        float4 lv = make_float4(ltaug[g.x], ltaug[g.y], ltaug[g.z], ltaug[g.w]);
        ((float4*)(out + 2 * KN))[i]      = tv;
        ((float4*)(out + 2 * KN + BN))[i] = lv;
    }
}

extern "C" void kernel_launch(void* const* d_in, const int* in_sizes, int n_in,
                              void* d_out, int out_size, void* d_ws, size_t ws_size,
                              hipStream_t stream)
{
    const float* x   = (const float*)d_in[0];
    const int*   gl  = (const int*)d_in[1];
    const float* W1  = (const float*)d_in[2];
    const float* b1  = (const float*)d_in[3];
    const float* W2  = (const float*)d_in[4];
    const float* b2  = (const float*)d_in[5];
    const float* W3  = (const float*)d_in[6];
    const float* b3  = (const float*)d_in[7];
    const float* wmu = (const float*)d_in[8];
    const float* bmu = (const float*)d_in[9];
    const float* wlv = (const float*)d_in[10];
    const float* blv = (const float*)d_in[11];
    float* out = (float*)d_out;

    float* ws     = (float*)d_ws;
    float* gsum   = ws;                          // KN*64 f32
    int*   counts = (int*)(gsum + KN * 64);      // KN
    int*   cursor = counts + KN;                 // KN
    float* taug   = (float*)(cursor + KN);       // KN
    float* ltaug  = taug + KN;                   // KN
    int2*  spk    = (int2*)(ltaug + KN);         // BN int2 (.x=orig row, .y=group)

    hipMemsetAsync(counts, 0, (size_t)KN * sizeof(int), stream);

    const int nb4 = (BN / 4 + 255) / 256;        // 977
    k_count  <<<nb4, 256, 0, stream>>>(gl, counts, (float4*)gsum);
    k_scan   <<<1, 1024, 0, stream>>>(counts, cursor);
    k_scatter<<<nb4, 256, 0, stream>>>(gl, cursor, spk);
    k_phase1 <<<NB1, TPB1, 0, stream>>>(x, spk, W1, b1, W2, b2, gsum);
    k_phase2 <<<KN / 64, 64, 0, stream>>>(gsum, counts, W3, b3, wmu, bmu, wlv, blv, out, taug, ltaug);
    k_phase3 <<<nb4, 256, 0, stream>>>(gl, taug, ltaug, out);
}

// Round 13
// 233.736 us; speedup vs baseline: 3.3302x; 1.1805x over previous
//
#include <hip/hip_runtime.h>

#define BN 1000000
#define KN 16384
#define HN 64
#define TPB 512
#define NW  8
#define CHROWS 256                      // rows per block-chunk (8 waves x 32 rows)
#define NB  512                         // persistent grid: 2 blocks/CU
#define NCHUNK ((BN + CHROWS - 1) / CHROWS) // 3907

typedef __bf16 bf16x8 __attribute__((ext_vector_type(8)));
typedef float  f32x4  __attribute__((ext_vector_type(4)));
typedef unsigned short u16x8 __attribute__((ext_vector_type(8)));

__device__ __forceinline__ unsigned short f2bf(float f) {
    return __builtin_bit_cast(unsigned short, (__bf16)f);   // HW v_cvt (RTNE)
}
__device__ __forceinline__ float bf2f(unsigned short b) {
    return (float)__builtin_bit_cast(__bf16, b);
}
__device__ __forceinline__ float silu_f(float v) {
    return v * __builtin_amdgcn_rcpf(1.0f + __expf(-v));
}
__device__ __forceinline__ f32x4 mfma16(bf16x8 a, bf16x8 b, f32x4 c) {
    return __builtin_amdgcn_mfma_f32_16x16x32_bf16(a, b, c, 0, 0, 0);
}

// ---- XLA ErfInv32 polynomial ----
__device__ __forceinline__ float erfinv_xla(float x) {
    float w = -log1pf(-x * x);
    float p;
    if (w < 5.0f) {
        w -= 2.5f;
        p = 2.81022636e-08f;
        p = fmaf(p, w, 3.43273939e-07f);
        p = fmaf(p, w, -3.5233877e-06f);
        p = fmaf(p, w, -4.39150654e-06f);
        p = fmaf(p, w, 0.00021858087f);
        p = fmaf(p, w, -0.00125372503f);
        p = fmaf(p, w, -0.00417768164f);
        p = fmaf(p, w, 0.246640727f);
        p = fmaf(p, w, 1.50140941f);
    } else {
        w = sqrtf(w) - 3.0f;
        p = -0.000200214257f;
        p = fmaf(p, w, 0.000100950558f);
        p = fmaf(p, w, 0.00134934322f);
        p = fmaf(p, w, -0.00367342844f);
        p = fmaf(p, w, 0.00573950773f);
        p = fmaf(p, w, -0.0076224613f);
        p = fmaf(p, w, 0.00943887047f);
        p = fmaf(p, w, 1.00167406f);
        p = fmaf(p, w, 2.83297682f);
    }
    return p * x;
}

// ---- jax.random.normal(key(42), (16384,)), threefry_partitionable: bits = out0^out1 ----
__device__ __forceinline__ float jax_eps16384(int gid) {
    const unsigned k0 = 0u, k1 = 42u, k2 = 0x1BD11BDAu ^ 0u ^ 42u;
    unsigned x0 = 0u + k0;
    unsigned x1 = (unsigned)gid + k1;
#define TF_RND(r) { x0 += x1; x1 = (x1 << (r)) | (x1 >> (32 - (r))); x1 ^= x0; }
    TF_RND(13) TF_RND(15) TF_RND(26) TF_RND(6)  x0 += k1; x1 += k2 + 1u;
    TF_RND(17) TF_RND(29) TF_RND(16) TF_RND(24) x0 += k2; x1 += k0 + 2u;
    TF_RND(13) TF_RND(15) TF_RND(26) TF_RND(6)  x0 += k0; x1 += k1 + 3u;
    TF_RND(17) TF_RND(29) TF_RND(16) TF_RND(24) x0 += k1; x1 += k2 + 4u;
    TF_RND(13) TF_RND(15) TF_RND(26) TF_RND(6)  x0 += k2; x1 += k0 + 5u;
#undef TF_RND
    unsigned bits = x0 ^ x1;
    float f = __uint_as_float((bits >> 9) | 0x3f800000u) - 1.0f;
    const float mn = -0.99999994f;
    float u = fmaxf(f * 2.0f + mn, mn);
    return 1.41421354f * erfinv_xla(u);
}

// ============ counting sort: histogram(+gsum zero), shuffle-scan, scatter ============
__global__ __launch_bounds__(256) void k_count(const int* __restrict__ gl,
                                               int* __restrict__ counts,
                                               float4* __restrict__ gz) {
    int i = blockIdx.x * 256 + threadIdx.x;
    const float4 z4 = make_float4(0.f, 0.f, 0.f, 0.f);
    for (int j = i; j < KN * HN / 4; j += 250112) gz[j] = z4;   // fold gsum memset in
    if (i < BN / 4) {
        int4 g = ((const int4*)gl)[i];
        atomicAdd(&counts[g.x], 1); atomicAdd(&counts[g.y], 1);
        atomicAdd(&counts[g.z], 1); atomicAdd(&counts[g.w], 1);
    }
}

__global__ __launch_bounds__(1024) void k_scan(const int* __restrict__ counts, int* __restrict__ cursor) {
    __shared__ int wtot[16];
    const int t = threadIdx.x, lane = t & 63, wv = t >> 6;
    const int4* c4 = (const int4*)counts;
    int4 q0 = c4[t * 4], q1 = c4[t * 4 + 1], q2 = c4[t * 4 + 2], q3 = c4[t * 4 + 3];
    int c[16] = {q0.x, q0.y, q0.z, q0.w, q1.x, q1.y, q1.z, q1.w,
                 q2.x, q2.y, q2.z, q2.w, q3.x, q3.y, q3.z, q3.w};
    int loc[16], s = 0;
    #pragma unroll
    for (int i = 0; i < 16; ++i) { loc[i] = s; s += c[i]; }
    const int own = s;
    #pragma unroll
    for (int off = 1; off < 64; off <<= 1) {      // inclusive wave scan
        int v = __shfl_up(s, off);
        if (lane >= off) s += v;
    }
    if (lane == 63) wtot[wv] = s;
    __syncthreads();
    int wbase = 0;
    #pragma unroll
    for (int w = 0; w < 16; ++w) wbase += (w < wv) ? wtot[w] : 0;
    const int ebase = wbase + s - own;            // exclusive prefix of this thread
    int o[16];
    #pragma unroll
    for (int i = 0; i < 16; ++i) o[i] = ebase + loc[i];
    int4* o4 = (int4*)cursor;
    o4[t * 4]     = make_int4(o[0],  o[1],  o[2],  o[3]);
    o4[t * 4 + 1] = make_int4(o[4],  o[5],  o[6],  o[7]);
    o4[t * 4 + 2] = make_int4(o[8],  o[9],  o[10], o[11]);
    o4[t * 4 + 3] = make_int4(o[12], o[13], o[14], o[15]);
}

__global__ __launch_bounds__(256) void k_scatter(const int* __restrict__ gl, int* __restrict__ cursor,
                                                 int2* __restrict__ spk) {
    int i = blockIdx.x * 256 + threadIdx.x;
    if (i < BN / 4) {
        int4 g = ((const int4*)gl)[i];
        int r = i * 4;
        int p0 = atomicAdd(&cursor[g.x], 1); spk[p0] = make_int2(r,     g.x);
        int p1 = atomicAdd(&cursor[g.y], 1); spk[p1] = make_int2(r + 1, g.y);
        int p2 = atomicAdd(&cursor[g.z], 1); spk[p2] = make_int2(r + 2, g.z);
        int p3 = atomicAdd(&cursor[g.w], 1); spk[p3] = make_int2(r + 3, g.w);
    }
}

// ============ phase 1: persistent MLP on sorted rows + segmented reduce ============
// 32 rows/wave (xr=32 VGPR) -> 4 waves/SIMD at 128 VGPR: 2x round-6 latency overlap.
__global__ __launch_bounds__(TPB, 4) void k_phase1(
    const float* __restrict__ x, const int2* __restrict__ spk,
    const float* __restrict__ W1, const float* __restrict__ b1,
    const float* __restrict__ W2, const float* __restrict__ b2,
    float* __restrict__ gsum)
{
    __shared__ __align__(16) unsigned short w1t[64 * 64];    // [j][k] bf16, swizzled
    __shared__ __align__(16) unsigned short w2t[64 * 64];
    __shared__ __align__(16) unsigned short xh[NW][32 * 64]; // per-wave: h1 then zT (4KB)
    __shared__ float b1s[64], b2s[64];
    __shared__ int sg_s[NW][32];

    const int t = threadIdx.x;
    const int wv = t >> 6, lane = t & 63;
    const int lj = lane & 15, lg = lane >> 4;

    // ---- stage W1^T, W2^T (bf16, swizzled) — once per block ----
    {
        const float4* W1v = (const float4*)W1;
        const float4* W2v = (const float4*)W2;
        #pragma unroll
        for (int i = 0; i < 2; ++i) {
            int e4 = i * TPB + t;
            int k  = e4 >> 4;
            int j0 = (e4 & 15) * 4;
            float4 a = W1v[e4];
            float4 b = W2v[e4];
            float av[4] = {a.x, a.y, a.z, a.w};
            float bv[4] = {b.x, b.y, b.z, b.w};
            #pragma unroll
            for (int c = 0; c < 4; ++c) {
                int j = j0 + c;
                int off = j * 128 + ((2 * k) ^ ((j & 7) << 4));
                *(unsigned short*)((char*)w1t + off) = f2bf(av[c]);
                *(unsigned short*)((char*)w2t + off) = f2bf(bv[c]);
            }
        }
        if (t < 64) { b1s[t] = b1[t]; b2s[t] = b2[t]; }
    }
    __syncthreads();   // the ONLY block barrier (startup)

    float bc1[4], bc2[4];
    #pragma unroll
    for (int ct = 0; ct < 4; ++ct) { bc1[ct] = b1s[ct * 16 + lj]; bc2[ct] = b2s[ct * 16 + lj]; }

    unsigned short* myx = &xh[wv][0];
    int2 rsA[2], rsB[2];

    // helper: issue spk loads for chunk c into dst (2 rows-of-16 per wave)
    auto load_spk = [&](int c, int2 (&dst)[2]) {
        int cc = c < NCHUNK - 1 ? c : NCHUNK - 1;
        #pragma unroll
        for (int rt = 0; rt < 2; ++rt) {
            int r = cc * CHROWS + wv * 32 + rt * 16 + lj;
            dst[rt] = spk[r < BN ? r : BN - 1];
        }
    };

    // one full chunk: gather (stalls on CUR), prefetch spk(c+NB) into NXT, compute
    auto iter = [&](int2 (&CUR)[2], int2 (&NXT)[2], int c) {
        // issue gathers for chunk c (addresses in CUR, already resident)
        float4 xr[2][4];
        #pragma unroll
        for (int rt = 0; rt < 2; ++rt) {
            const float* xp = x + (size_t)CUR[rt].x * 64 + lg * 8;
            xr[rt][0] = *(const float4*)(xp);
            xr[rt][1] = *(const float4*)(xp + 4);
            xr[rt][2] = *(const float4*)(xp + 32);
            xr[rt][3] = *(const float4*)(xp + 36);
        }
        // prefetch next chunk's spk
        load_spk(c + NB, NXT);
        // sg for chunk c (wave-private)
        if (lg == 0) {
            #pragma unroll
            for (int rt = 0; rt < 2; ++rt) {
                int r = c * CHROWS + wv * 32 + rt * 16 + lj;
                sg_s[wv][rt * 16 + lj] = (r < BN) ? CUR[rt].y : -1;
            }
        }
        // convert to bf16 A-fragments (waits on xr as values arrive)
        bf16x8 af[2][2];
        #pragma unroll
        for (int rt = 0; rt < 2; ++rt)
            #pragma unroll
            for (int kk = 0; kk < 2; ++kk) {
                float4 a = xr[rt][kk * 2], b = xr[rt][kk * 2 + 1];
                u16x8 u;
                u[0] = f2bf(a.x); u[1] = f2bf(a.y); u[2] = f2bf(a.z); u[3] = f2bf(a.w);
                u[4] = f2bf(b.x); u[5] = f2bf(b.y); u[6] = f2bf(b.z); u[7] = f2bf(b.w);
                af[rt][kk] = __builtin_bit_cast(bf16x8, u);
            }

        f32x4 acc[2][4];
        #pragma unroll
        for (int a = 0; a < 2; ++a)
            #pragma unroll
            for (int b = 0; b < 4; ++b) acc[a][b] = f32x4{0.f, 0.f, 0.f, 0.f};
        // layer 1 (A from regs, B from LDS)
        #pragma unroll
        for (int kk = 0; kk < 2; ++kk) {
            const int kbyte = kk * 64 + lg * 16;
            bf16x8 bw[4];
            #pragma unroll
            for (int ct = 0; ct < 4; ++ct) {
                int row = ct * 16 + lj;
                bw[ct] = *(const bf16x8*)((char*)w1t + row * 128 + (kbyte ^ ((row & 7) << 4)));
            }
            #pragma unroll
            for (int rt = 0; rt < 2; ++rt)
                #pragma unroll
                for (int ct = 0; ct < 4; ++ct)
                    acc[rt][ct] = mfma16(af[rt][kk], bw[ct], acc[rt][ct]);
        }
        // epilogue 1: h1 -> own-wave LDS (A-layout rows 0..31, swizzled)
        #pragma unroll
        for (int rt = 0; rt < 2; ++rt) {
            #pragma unroll
            for (int ct = 0; ct < 4; ++ct) {
                f32x4 v = acc[rt][ct];
                #pragma unroll
                for (int rg = 0; rg < 4; ++rg) {
                    int row = rt * 16 + lg * 4 + rg;
                    int col = ct * 16 + lj;
                    float h = silu_f(v[rg] + bc1[ct]);
                    int off = row * 128 + ((2 * col) ^ ((row & 7) << 4));
                    *(unsigned short*)((char*)myx + off) = f2bf(h);
                }
                acc[rt][ct] = f32x4{0.f, 0.f, 0.f, 0.f};
            }
        }
        // layer 2 (A from own-wave LDS, B from LDS)
        #pragma unroll
        for (int kk = 0; kk < 2; ++kk) {
            const int kbyte = kk * 64 + lg * 16;
            bf16x8 bw[4];
            #pragma unroll
            for (int ct = 0; ct < 4; ++ct) {
                int row = ct * 16 + lj;
                bw[ct] = *(const bf16x8*)((char*)w2t + row * 128 + (kbyte ^ ((row & 7) << 4)));
            }
            #pragma unroll
            for (int rt = 0; rt < 2; ++rt) {
                int row = rt * 16 + lj;
                bf16x8 aw = *(const bf16x8*)((char*)myx + row * 128 + (kbyte ^ ((row & 7) << 4)));
                #pragma unroll
                for (int ct = 0; ct < 4; ++ct)
                    acc[rt][ct] = mfma16(aw, bw[ct], acc[rt][ct]);
            }
        }
        // epilogue 2: zT col-major (col stride 64B, swizzle (col&3)<<4), packed ushort4
        #pragma unroll
        for (int rt = 0; rt < 2; ++rt) {
            #pragma unroll
            for (int ct = 0; ct < 4; ++ct) {
                f32x4 v = acc[rt][ct];
                int col  = ct * 16 + lj;
                int row0 = rt * 16 + lg * 4;
                ushort4 pk;
                pk.x = f2bf(silu_f(v[0] + bc2[ct]));
                pk.y = f2bf(silu_f(v[1] + bc2[ct]));
                pk.z = f2bf(silu_f(v[2] + bc2[ct]));
                pk.w = f2bf(silu_f(v[3] + bc2[ct]));
                *(ushort4*)((char*)myx + col * 64 + ((2 * row0) ^ ((col & 3) << 4))) = pk;
            }
        }
        // segmented reduce: lane owns col; 8 rows per ds_read_b128 (4 blocks)
        {
            const int c2 = lane;
            const char* zT = (const char*)myx;
            float vsum = 0.0f;
            int curg = -2;
            #pragma unroll
            for (int blk = 0; blk < 4; ++blk) {
                u16x8 v = *(const u16x8*)(zT + c2 * 64 + ((16 * blk) ^ ((c2 & 3) << 4)));
                int4 ga = *(const int4*)(&sg_s[wv][blk * 8]);
                int4 gb = *(const int4*)(&sg_s[wv][blk * 8 + 4]);
                int gs[8] = {ga.x, ga.y, ga.z, ga.w, gb.x, gb.y, gb.z, gb.w};
                #pragma unroll
                for (int j = 0; j < 8; ++j) {
                    int g = gs[j];
                    if (g != curg) {
                        if (curg >= 0) atomicAdd(&gsum[curg * 64 + c2], vsum);
                        vsum = 0.0f;
                        curg = g;
                    }
                    vsum += bf2f(v[j]);
                }
            }
            if (curg >= 0) atomicAdd(&gsum[curg * 64 + c2], vsum);
        }
    };

    // ---- persistent loop, 1-deep spk ping-pong ----
    int c = blockIdx.x;
    load_spk(c, rsA);
    while (true) {
        iter(rsA, rsB, c); c += NB; if (c >= NCHUNK) break;
        iter(rsB, rsA, c); c += NB; if (c >= NCHUNK) break;
    }
}

// ============ phase 2: group head + reparam sample ============
__global__ __launch_bounds__(64) void k_phase2(
    const float* __restrict__ gsum, const int* __restrict__ counts,
    const float* __restrict__ W3, const float* __restrict__ b3,
    const float* __restrict__ wmu, const float* __restrict__ bmu,
    const float* __restrict__ wlv, const float* __restrict__ blv,
    float* __restrict__ out, float* __restrict__ taug, float* __restrict__ ltaug)
{
    __shared__ __align__(16) float w3t[64 * 64];   // [j][k]
    __shared__ float b3s[64], wmus[64], wlvs[64];
    const int t = threadIdx.x;
    for (int i = 0; i < 64; ++i) w3t[t * 64 + i] = W3[i * 64 + t];
    b3s[t] = b3[t]; wmus[t] = wmu[t]; wlvs[t] = wlv[t];
    __syncthreads();

    const int gid = blockIdx.x * 64 + t;
    const float inv = 1.0f / (float)counts[gid];
    float gf[64];
    #pragma unroll
    for (int i = 0; i < 16; ++i) {
        float4 v = *(const float4*)(gsum + (size_t)gid * 64 + i * 4);
        gf[i * 4 + 0] = v.x * inv; gf[i * 4 + 1] = v.y * inv;
        gf[i * 4 + 2] = v.z * inv; gf[i * 4 + 3] = v.w * inv;
    }
    float mu = bmu[0], lv = blv[0];
    for (int j = 0; j < 64; ++j) {
        float a = b3s[j];
        const float4* wr = (const float4*)(w3t + j * 64);
        #pragma unroll
        for (int k = 0; k < 16; ++k) {
            float4 wv = wr[k];
            a += gf[k * 4 + 0] * wv.x + gf[k * 4 + 1] * wv.y
               + gf[k * 4 + 2] * wv.z + gf[k * 4 + 3] * wv.w;
        }
        float h = silu_f(a);
        mu += h * wmus[j];
        lv += h * wlvs[j];
    }
    lv = fminf(fmaxf(lv, -10.0f), 4.0f);
    float sd  = __expf(0.5f * lv);
    float eps = jax_eps16384(gid);
    float lt  = mu + sd * eps;
    out[gid]      = mu;
    out[KN + gid] = lv;
    taug[gid]  = __expf(lt);
    ltaug[gid] = lt;
}

// ============ phase 3: broadcast per-group sample to reflections ============
__global__ __launch_bounds__(256) void k_phase3(
    const int* __restrict__ gl, const float* __restrict__ taug,
    const float* __restrict__ ltaug, float* __restrict__ out)
{
    int i = blockIdx.x * 256 + threadIdx.x;
    if (i < BN / 4) {
        int4 g = ((const int4*)gl)[i];
        float4 tv = make_float4(taug[g.x],  taug[g.y],  taug[g.z],  taug[g.w]);
        float4 lv = make_float4(ltaug[g.x], ltaug[g.y], ltaug[g.z], ltaug[g.w]);
        ((float4*)(out + 2 * KN))[i]      = tv;
        ((float4*)(out + 2 * KN + BN))[i] = lv;
    }
}

extern "C" void kernel_launch(void* const* d_in, const int* in_sizes, int n_in,
                              void* d_out, int out_size, void* d_ws, size_t ws_size,
                              hipStream_t stream)
{
    const float* x   = (const float*)d_in[0];
    const int*   gl  = (const int*)d_in[1];
    const float* W1  = (const float*)d_in[2];
    const float* b1  = (const float*)d_in[3];
    const float* W2  = (const float*)d_in[4];
    const float* b2  = (const float*)d_in[5];
    const float* W3  = (const float*)d_in[6];
    const float* b3  = (const float*)d_in[7];
    const float* wmu = (const float*)d_in[8];
    const float* bmu = (const float*)d_in[9];
    const float* wlv = (const float*)d_in[10];
    const float* blv = (const float*)d_in[11];
    float* out = (float*)d_out;

    float* ws     = (float*)d_ws;
    float* gsum   = ws;                          // KN*HN f32
    int*   counts = (int*)(gsum + KN * HN);      // KN
    int*   cursor = counts + KN;                 // KN
    float* taug   = (float*)(cursor + KN);       // KN
    float* ltaug  = taug + KN;                   // KN
    int2*  spk    = (int2*)(ltaug + KN);         // BN int2 (.x=orig row, .y=group)

    hipMemsetAsync(counts, 0, (size_t)KN * sizeof(int), stream);

    const int nb4 = (BN / 4 + 255) / 256;        // 977
    k_count  <<<nb4, 256, 0, stream>>>(gl, counts, (float4*)gsum);
    k_scan   <<<1, 1024, 0, stream>>>(counts, cursor);
    k_scatter<<<nb4, 256, 0, stream>>>(gl, cursor, spk);
    k_phase1 <<<NB, TPB, 0, stream>>>(x, spk, W1, b1, W2, b2, gsum);
    k_phase2 <<<KN / 64, 64, 0, stream>>>(gsum, counts, W3, b3, wmu, bmu, wlv, blv, out, taug, ltaug);
    k_phase3 <<<nb4, 256, 0, stream>>>(gl, taug, ltaug, out);
}